// Round 1
// baseline (597.424 us; speedup 1.0000x reference)
//
#include <hip/hip_runtime.h>
#include <stdint.h>

// Problem constants
#define BB 8192
#define TT 512
#define FF 24
#define HH 12

// Mapping: 8 lanes per chain, 8 chains per 64-thread (1-wave) block.
#define CHAINS 8
#define TC 16                          // timesteps per staged chunk
#define CHUNKS (TT / TC)               // 32
#define CHUNK_BYTES (TC * FF * 4)      // 1536 bytes of x per chain per chunk
#define LDS_STRIDE (CHUNK_BYTES + 16)  // 1552 = 97*16 -> breaks bank aliasing
#define NLOAD 13                       // ceil(CHAINS*LDS_STRIDE / 1024) = ceil(12416/1024)
#define BUF_BYTES (NLOAD * 1024)       // 13312 (global_load_lds covers full 1KB windows)
#define X_CHAIN_BYTES (TT * FF * 4)    // 49152

typedef const __attribute__((address_space(1))) void* gptr_t;
typedef __attribute__((address_space(3))) void* lptr_t;

__device__ __forceinline__ float fast_tanh(float x) {
  // tanh(x) = 1 - 2/(exp(2x)+1); v_exp + v_rcp, saturates correctly at +/-inf
  float e = __expf(x + x);
  float r = __builtin_amdgcn_rcpf(e + 1.0f);
  return fmaf(-2.0f, r, 1.0f);
}

__global__ __launch_bounds__(64, 1) void rnn_fused(
    const float* __restrict__ x, const float* __restrict__ W_ih,
    const float* __restrict__ b_ih, const float* __restrict__ W_hh,
    const float* __restrict__ b_hh, const float* __restrict__ W1,
    const float* __restrict__ b1, const float* __restrict__ W2,
    const float* __restrict__ b2, const float* __restrict__ W3,
    const float* __restrict__ b3, float* __restrict__ out) {
  __shared__ __align__(16) char smem[2 * BUF_BYTES];

  const int lane  = threadIdx.x;        // 0..63
  const int chain = lane >> 3;          // 0..7  (local chain)
  const int m     = lane & 3;           // output-block owner: rows 3m..3m+2
  const int sub   = (lane >> 2) & 1;    // f-half owner: f = sub*12 .. sub*12+11

  // ---------------- weights into registers ----------------
  float wih[3][12];   // W_ih[3m+r][sub*12 + j]
  float whh[3][12];   // W_hh[3m+r][perm col], perm matches butterfly h order
  float bcv[3];       // b_ih + b_hh for owned rows
  const int r0 = 3 * m;
#pragma unroll
  for (int r = 0; r < 3; ++r) {
    const float4* wr = (const float4*)(W_ih + (r0 + r) * FF + sub * 12);
    float4 a = wr[0], b = wr[1], c = wr[2];
    wih[r][0] = a.x; wih[r][1] = a.y; wih[r][2]  = a.z; wih[r][3]  = a.w;
    wih[r][4] = b.x; wih[r][5] = b.y; wih[r][6]  = b.z; wih[r][7]  = b.w;
    wih[r][8] = c.x; wih[r][9] = c.y; wih[r][10] = c.z; wih[r][11] = c.w;
    bcv[r] = b_ih[r0 + r] + b_hh[r0 + r];
    // h register order after butterfly: blocks [m, m^1, m^2, m^3] (3 rows each).
    // Load W_hh columns permuted to match so the dot product needs no shuffling.
#pragma unroll
    for (int k = 0; k < 12; ++k) {
      const int K = k / 3, cc = k % 3;          // compile-time (unrolled)
      const int col = 3 * (m ^ K) + cc;
      whh[r][k] = W_hh[(r0 + r) * HH + col];
    }
  }

  // ---------------- per-lane staging offsets ----------------
  // LDS layout per buffer: chain c at [c*1552, c*1552+1536), +16B pad.
  // global_load_lds instr k fills LDS [k*1024, k*1024+1024), lane slot = lane*16.
  unsigned voff[NLOAD];
#pragma unroll
  for (int k = 0; k < NLOAD; ++k) {
    unsigned off = (unsigned)(k * 1024) + (unsigned)(lane * 16);
    unsigned c = off / LDS_STRIDE;
    unsigned w = off - c * LDS_STRIDE;
    bool ok = (c < CHAINS) && (w < CHUNK_BYTES);
    voff[k] = ok ? (c * X_CHAIN_BYTES + w) : 0u;  // pad lanes -> harmless load of x[0]
  }

  const char* xg = (const char*)x + (size_t)blockIdx.x * CHAINS * X_CHAIN_BYTES;

  // stage chunk 0 -> buffer 0
#pragma unroll
  for (int k = 0; k < NLOAD; ++k)
    __builtin_amdgcn_global_load_lds((gptr_t)(xg + voff[k]),
                                     (lptr_t)(smem + k * 1024), 16, 0, 0);

  float h[12];
#pragma unroll
  for (int k = 0; k < 12; ++k) h[k] = 0.0f;

  // ---------------- main recurrence ----------------
  for (int ch = 0; ch < CHUNKS; ++ch) {
    if (ch + 1 < CHUNKS) {
      const char* gb = xg + (size_t)(ch + 1) * CHUNK_BYTES;
      char* lb = smem + ((ch + 1) & 1) * BUF_BYTES;
#pragma unroll
      for (int k = 0; k < NLOAD; ++k)
        __builtin_amdgcn_global_load_lds((gptr_t)(gb + voff[k]),
                                         (lptr_t)(lb + k * 1024), 16, 0, 0);
      // 13 just issued for next chunk; wait for everything older (= this chunk)
      asm volatile("s_waitcnt vmcnt(13)" ::: "memory");
    } else {
      asm volatile("s_waitcnt vmcnt(0)" ::: "memory");
    }

    const char* bufc = smem + (ch & 1) * BUF_BYTES + chain * LDS_STRIDE + sub * 48;
#pragma unroll
    for (int t = 0; t < TC; ++t) {
      const float4* xp = (const float4*)(bufc + t * 96);
      float4 x0 = xp[0], x1 = xp[1], x2 = xp[2];
      float xs[12] = {x0.x, x0.y, x0.z, x0.w, x1.x, x1.y,
                      x1.z, x1.w, x2.x, x2.y, x2.z, x2.w};
      float av[3];
#pragma unroll
      for (int r = 0; r < 3; ++r) {
        // input projection over this lane's f-half (2 accs for ILP)
        float pa = 0.0f, pb = 0.0f;
#pragma unroll
        for (int j = 0; j < 6; ++j) {
          pa = fmaf(wih[r][j], xs[j], pa);
          pb = fmaf(wih[r][j + 6], xs[j + 6], pb);
        }
        float p = pa + pb;
        p += __shfl_xor(p, 4);  // combine f-halves (bit-identical on both subs)
        // recurrent part (duplicated on both subs; h/whh identical there)
        float ra = 0.0f, rb = 0.0f;
#pragma unroll
        for (int k = 0; k < 6; ++k) {
          ra = fmaf(whh[r][k], h[k], ra);
          rb = fmaf(whh[r][k + 6], h[k + 6], rb);
        }
        av[r] = fast_tanh(p + (ra + rb) + bcv[r]);
      }
      // butterfly broadcast: h regs end as blocks [m, m^1, m^2, m^3]
      float bv[3], cv[3], dv[3];
#pragma unroll
      for (int r = 0; r < 3; ++r) bv[r] = __shfl_xor(av[r], 1);
#pragma unroll
      for (int r = 0; r < 3; ++r) {
        cv[r] = __shfl_xor(av[r], 2);
        dv[r] = __shfl_xor(bv[r], 2);
      }
#pragma unroll
      for (int r = 0; r < 3; ++r) {
        h[r] = av[r]; h[3 + r] = bv[r]; h[6 + r] = cv[r]; h[9 + r] = dv[r];
      }
    }
  }

  // ---------------- MLP head (once per chain; lane m==0,sub==0 has natural h order)
  if ((lane & 7) == 0) {
    float o1[12], o2[12];
#pragma unroll
    for (int i = 0; i < 12; ++i) {
      float acc = b1[i];
#pragma unroll
      for (int j = 0; j < 12; ++j) acc = fmaf(W1[i * 12 + j], h[j], acc);
      o1[i] = fmaxf(acc, 0.0f);
    }
#pragma unroll
    for (int i = 0; i < 12; ++i) {
      float acc = b2[i];
#pragma unroll
      for (int j = 0; j < 12; ++j) acc = fmaf(W2[i * 12 + j], o1[j], acc);
      o2[i] = fmaxf(acc, 0.0f);
    }
    float o = b3[0];
#pragma unroll
    for (int j = 0; j < 12; ++j) o = fmaf(W3[j], o2[j], o);
    out[blockIdx.x * CHAINS + chain] = o;
  }
}

extern "C" void kernel_launch(void* const* d_in, const int* in_sizes, int n_in,
                              void* d_out, int out_size, void* d_ws, size_t ws_size,
                              hipStream_t stream) {
  (void)in_sizes; (void)n_in; (void)d_ws; (void)ws_size; (void)out_size;
  const float* x    = (const float*)d_in[0];
  const float* W_ih = (const float*)d_in[1];
  const float* b_ih = (const float*)d_in[2];
  const float* W_hh = (const float*)d_in[3];
  const float* b_hh = (const float*)d_in[4];
  const float* W1   = (const float*)d_in[5];
  const float* b1   = (const float*)d_in[6];
  const float* W2   = (const float*)d_in[7];
  const float* b2   = (const float*)d_in[8];
  const float* W3   = (const float*)d_in[9];
  const float* b3   = (const float*)d_in[10];

  rnn_fused<<<dim3(BB / CHAINS), dim3(64), 0, stream>>>(
      x, W_ih, b_ih, W_hh, b_hh, W1, b1, W2, b2, W3, b3, (float*)d_out);
}